// Round 6
// baseline (451.210 us; speedup 1.0000x reference)
//
#include <hip/hip_runtime.h>
#include <hip/hip_bf16.h>

// GCN 2-layer + mean-pool + log_softmax on gfx950.
// R16: dispatch-count attack (9 -> 6; ~7us gap per dispatch measured by
//      sum-of-kernels vs wall): scanA+scanBC fused into ONE single-block
//      1024-thr scan (also zeroes pooled); lsm folded into agg2pool via
//      completion-ticket (threadfence + atomicAdd(done), last block runs
//      log-softmax). agg1f gets __launch_bounds__(256,4) to lift the
//      compiler's 32-VGPR occupancy cap (A/B probe: agg1f has been ~45us
//      across 4 structural variants, always at VGPR=32). Everything else
//      kept from R15 (staged csr window, stride-132 W2 LDS, R12 cg1 fusion).

#define NN 50000
#define EE 600000
#define FIN 128
#define HH 128
#define CC 16
#define GG 500
#define ETOT (EE + NN)   // 650000
#define WTS 140          // gemm1 wt row stride
#define CBLK ((EE + 255) / 256)   // 2344 count blocks in fused cg1
#define A1CAP 1024       // agg1f block csr window (4 nodes)
#define A2CAP 2048       // agg2pool block csr window (16 nodes)

typedef unsigned short ushort_t;
typedef unsigned int uint_t;

typedef __attribute__((ext_vector_type(8))) short bf16x8;
typedef __attribute__((ext_vector_type(4))) ushort_t u16x4;
typedef __attribute__((ext_vector_type(4))) float f32x4;
typedef __attribute__((ext_vector_type(2))) float f32x2;

__device__ inline ushort_t f2bf(float f) {
    uint_t u = __float_as_uint(f);
    u = (u + 0x7FFFu + ((u >> 16) & 1u)) >> 16;   // RNE
    return (ushort_t)u;
}
__device__ inline float bf2f(ushort_t b) {
    return __uint_as_float(((uint_t)b) << 16);
}
__device__ inline ushort_t f2h(float f) {
    _Float16 h = (_Float16)f; ushort_t u; __builtin_memcpy(&u, &h, 2); return u;
}
__device__ inline float h2f(ushort_t u) {
    _Float16 h; __builtin_memcpy(&h, &u, 2); return (float)h;
}

// ---------------- init: cnt + done ticket ----------------
__global__ void init_kernel(int* cnt, int* done) {
    int i = blockIdx.x * blockDim.x + threadIdx.x;
    if (i < NN) cnt[i] = 0;
    if (i == 0) *done = 0;
}

// ---------------- fused count + GEMM1 ----------------------------------------
// blocks [0, CBLK): seq[e] = atomicAdd(&cnt[dst], 1)  (memory-side atomics,
//   latency-bound). blocks [CBLK, ...): hb8 = fp8(x @ W1) overlapping the
//   atomic tail on otherwise-idle VALU/MFMA pipes.
__global__ __launch_bounds__(256) void cg1_kernel(const int* __restrict__ edge_dst,
                                                  int* __restrict__ cnt,
                                                  int* __restrict__ seq,
                                                  const float* __restrict__ x,
                                                  const float* __restrict__ W1,
                                                  unsigned char* __restrict__ hb8) {
    __shared__ ushort_t xs[64 * 136];
    __shared__ ushort_t wt[128 * WTS];
    if (blockIdx.x < CBLK) {
        int idx = blockIdx.x * 256 + threadIdx.x;
        if (idx < EE) seq[idx] = atomicAdd(&cnt[edge_dst[idx]], 1);
        return;
    }
    int t = threadIdx.x;
    int row0 = (blockIdx.x - CBLK) * 64;
    for (int i = 0; i < 8; i++) {
        int slot = t + i * 256;
        int r = slot >> 5, k4 = slot & 31;
        int gr = row0 + r;
        float4 v = (gr < NN) ? ((const float4*)x)[gr * 32 + k4]
                             : make_float4(0.f, 0.f, 0.f, 0.f);
        u16x4 bv = { f2bf(v.x), f2bf(v.y), f2bf(v.z), f2bf(v.w) };
        *(u16x4*)(&xs[r * 136 + k4 * 4]) = bv;
    }
    for (int i = 0; i < 16; i++) {
        int idx = t + i * 256;
        int c = idx & 127, k4 = idx >> 7;
        u16x4 bv = { f2bf(W1[(4 * k4 + 0) * HH + c]),
                     f2bf(W1[(4 * k4 + 1) * HH + c]),
                     f2bf(W1[(4 * k4 + 2) * HH + c]),
                     f2bf(W1[(4 * k4 + 3) * HH + c]) };
        *(u16x4*)(&wt[c * WTS + k4 * 4]) = bv;
    }
    __syncthreads();

    int wave = t >> 6, lane = t & 63;
    int m = lane & 15, quad = lane >> 4;
    f32x4 acc[8];
    for (int ct = 0; ct < 8; ct++) acc[ct] = (f32x4)(0.0f);
    for (int ko = 0; ko < 4; ko++) {
        bf16x8 a = *(const bf16x8*)(&xs[(16 * wave + m) * 136 + ko * 32 + quad * 8]);
        for (int ct = 0; ct < 8; ct++) {
            bf16x8 b = *(const bf16x8*)(&wt[(ct * 16 + m) * WTS + ko * 32 + quad * 8]);
            acc[ct] = __builtin_amdgcn_mfma_f32_16x16x32_bf16(a, b, acc[ct], 0, 0, 0);
        }
    }
    for (int ct = 0; ct < 8; ct++) {
        int gcol = ct * 16 + m;
        for (int r = 0; r < 4; r++) {
            int grow = row0 + wave * 16 + quad * 4 + r;
            if (grow < NN) {
                int p = __builtin_amdgcn_cvt_pk_fp8_f32(acc[ct][r], 0.0f, 0, false);
                hb8[(size_t)grow * HH + gcol] = (unsigned char)(p & 0xFF);
            }
        }
    }
}

// ---------------- fused single-block scan (rowptr + dis + gstart + pooled=0) --
// 1024 threads, thread t owns contiguous chunk [t*49, t*49+49). Pass A: chunk
// sums -> wave shfl scan -> wave-partial scan. Pass B: re-read cnt, write
// exclusive rowptr, dis, graph-boundary gstart. Also zeroes pooled (needed
// before agg2pl, guaranteed by dispatch order).
__global__ __launch_bounds__(1024) void scanF_kernel(const int* __restrict__ cnt,
                                                     int* __restrict__ rowptr,
                                                     float* __restrict__ dis,
                                                     const int* __restrict__ batch,
                                                     int* __restrict__ gstart,
                                                     float* __restrict__ pooled) {
    __shared__ int wpart[16];
    int t = threadIdx.x;
    const int CH = (NN + 1023) / 1024;   // 49
    int base = t * CH;
    int s = 0;
    for (int j = 0; j < CH; j++) {
        int i = base + j;
        if (i < NN) s += cnt[i] + 1;     // +1 self-loop
    }
    int lane = t & 63, wv = t >> 6;
    int inc = s;
    for (int off = 1; off < 64; off <<= 1) {
        int n = __shfl_up(inc, off);
        if (lane >= off) inc += n;
    }
    if (lane == 63) wpart[wv] = inc;
    __syncthreads();
    if (t < 16) {
        int v = wpart[t];
        int in2 = v;
        for (int off = 1; off < 16; off <<= 1) {
            int n = __shfl_up(in2, off);
            if (t >= off) in2 += n;
        }
        wpart[t] = in2 - v;              // exclusive wave prefix
    }
    __syncthreads();
    int run = wpart[wv] + inc - s;       // exclusive prefix for chunk head
    for (int j = 0; j < CH; j++) {
        int i = base + j;
        if (i < NN) {
            int d = cnt[i] + 1;
            rowptr[i] = run;
            run += d;
            dis[i] = rsqrtf((float)d);
            int b = batch[i];
            int bp = (i == 0) ? -1 : batch[i - 1];
            for (int g = bp + 1; g <= b; ++g) gstart[g] = i;
            if (i == NN - 1) {
                for (int g = b + 1; g <= GG; ++g) gstart[g] = NN;
            }
        }
    }
    if (t == 0) rowptr[NN] = ETOT;
    for (int i = t; i < GG * CC; i += 1024) pooled[i] = 0.0f;
}

// ---------------- CSR fill: entry = src | fp16(dis[src])<<16 ----------------
__global__ void fill_kernel(const int* __restrict__ edge_src,
                            const int* __restrict__ edge_dst,
                            const float* __restrict__ dis,
                            const int* __restrict__ rowptr,
                            const int* __restrict__ seq,
                            uint_t* __restrict__ csr) {
    int idx = blockIdx.x * blockDim.x + threadIdx.x;
    if (idx < EE) {
        int s = edge_src[idx], d = edge_dst[idx];
        csr[rowptr[d] + seq[idx]] = (uint_t)s | ((uint_t)f2h(dis[s]) << 16);
    } else if (idx < ETOT) {
        int n = idx - EE;
        csr[rowptr[n + 1] - 1] = (uint_t)n | ((uint_t)f2h(dis[n]) << 16);
    }
}

// ---------------- agg1 + in-LDS layer-2, LDS-staged csr window ----------------
// Gather structure = proven R10 (1 node/wave, 8 edge slots x 8 feature-lanes,
// 2-deep). Block csr window staged coalesced into LDS (cap + fallback). W2
// LDS table stride 132 (exact 2-per-bank, free). launch_bounds(256,4) lifts
// the compiler's 32-VGPR occupancy cap (probe: kernel pinned ~45us at VGPR=32
// across 4 structural variants).
__global__ __launch_bounds__(256, 4) void agg1f_kernel(const unsigned char* __restrict__ hb8,
                                                       const int* __restrict__ rowptr,
                                                       const uint_t* __restrict__ csr,
                                                       const float* __restrict__ dis,
                                                       const float* __restrict__ b1,
                                                       const float* __restrict__ W2,
                                                       ushort_t* __restrict__ h2b) {
    __shared__ uint_t w2s[8 * 132];      // 4224 B
    __shared__ uint_t ecsr[A1CAP];       // 4096 B
    int t = threadIdx.x;
    int node0 = blockIdx.x * 4;
    int wave = t >> 6, lane = t & 63;
    int node = node0 + wave;
    int slot = lane >> 3, sub = lane & 7;
    int wbeg = rowptr[node0];
    int wcap = rowptr[node0 + 4];
    int e0 = rowptr[node], e1 = rowptr[node + 1];
    float dn = dis[node];
    {
        const float2* W2v = (const float2*)W2;   // W2v[k*8+sl] = W2[k][2sl..2sl+1]
        for (int i = t; i < HH * 8; i += 256) {
            int k = i >> 3, sl = i & 7;
            float2 wv = W2v[i];
            w2s[(k >> 4) * 132 + (k & 15) * 8 + sl] =
                (uint_t)f2bf(wv.x) | ((uint_t)f2bf(wv.y) << 16);
        }
    }
    int wlen = min(wcap - wbeg, A1CAP);
    for (int i = t; i < wlen; i += 256) ecsr[i] = csr[wbeg + i];
    __syncthreads();   // start-barrier: all waves arrive together (no skew)
    int wend = wbeg + wlen;

    float acc[16];
    for (int j = 0; j < 16; j++) acc[j] = 0.0f;
    for (int e = e0 + slot; e < e1; e += 16) {
        uint_t ent0;
        if (e < wend) ent0 = ecsr[e - wbeg]; else ent0 = csr[e];
        bool has2 = (e + 8) < e1;
        uint_t ent1 = ent0;
        if (has2) {
            if (e + 8 < wend) ent1 = ecsr[e + 8 - wbeg]; else ent1 = csr[e + 8];
        }
        uint4 hv0 = *(const uint4*)(hb8 + (size_t)(ent0 & 0xFFFFu) * HH + sub * 16);
        uint4 hv1 = has2 ? *(const uint4*)(hb8 + (size_t)(ent1 & 0xFFFFu) * HH + sub * 16)
                         : make_uint4(0, 0, 0, 0);
        float w0 = h2f((ushort_t)(ent0 >> 16));
        uint_t words0[4] = { hv0.x, hv0.y, hv0.z, hv0.w };
        for (int q = 0; q < 4; q++) {
            f32x2 lo = __builtin_amdgcn_cvt_pk_f32_fp8(words0[q], false);
            f32x2 hi = __builtin_amdgcn_cvt_pk_f32_fp8(words0[q], true);
            acc[q * 4 + 0] += w0 * lo[0];
            acc[q * 4 + 1] += w0 * lo[1];
            acc[q * 4 + 2] += w0 * hi[0];
            acc[q * 4 + 3] += w0 * hi[1];
        }
        if (has2) {
            float w1 = h2f((ushort_t)(ent1 >> 16));
            uint_t words1[4] = { hv1.x, hv1.y, hv1.z, hv1.w };
            for (int q = 0; q < 4; q++) {
                f32x2 lo = __builtin_amdgcn_cvt_pk_f32_fp8(words1[q], false);
                f32x2 hi = __builtin_amdgcn_cvt_pk_f32_fp8(words1[q], true);
                acc[q * 4 + 0] += w1 * lo[0];
                acc[q * 4 + 1] += w1 * lo[1];
                acc[q * 4 + 2] += w1 * hi[0];
                acc[q * 4 + 3] += w1 * hi[1];
            }
        }
    }
    for (int j = 0; j < 16; j++) {
        acc[j] += __shfl_xor(acc[j], 8);
        acc[j] += __shfl_xor(acc[j], 16);
        acc[j] += __shfl_xor(acc[j], 32);
    }
    const float4* b1v = (const float4*)(b1 + sub * 16);
    float4 bb[4] = { b1v[0], b1v[1], b1v[2], b1v[3] };
    const float* bbf = (const float*)bb;
    float p0 = 0.0f, p1 = 0.0f;
    int wbase = sub * 132 + slot;
    for (int j = 0; j < 16; j++) {
        float h = fmaxf(dn * acc[j] + bbf[j], 0.0f);
        uint_t w = w2s[wbase + j * 8];
        p0 += h * __uint_as_float(w << 16);            // W2[sub*16+j][2slot]
        p1 += h * __uint_as_float(w & 0xFFFF0000u);    // W2[sub*16+j][2slot+1]
    }
    p0 += __shfl_xor(p0, 1); p0 += __shfl_xor(p0, 2); p0 += __shfl_xor(p0, 4);
    p1 += __shfl_xor(p1, 1); p1 += __shfl_xor(p1, 2); p1 += __shfl_xor(p1, 4);
    if (sub == 0) {
        uint_t pk = (uint_t)f2bf(p0) | ((uint_t)f2bf(p1) << 16);
        *(uint_t*)(h2b + (size_t)node * CC + 2 * slot) = pk;
    }
}

// ---------------- agg2 + pool + log_softmax (completion ticket) ---------------
// 1 node/wave, 16 nodes/block (1024 thr), LDS-staged csr window. After the
// pool atomics, last finishing block (device-scope ticket) computes the
// mean + log_softmax for all 500 graphs. 8000 = 500*16 elements, groups of
// 16 threads per graph, stride 1024 preserves lane%16 == channel.
__global__ __launch_bounds__(1024) void agg2pl_kernel(const ushort_t* __restrict__ h2b,
                                                      const int* __restrict__ rowptr,
                                                      const uint_t* __restrict__ csr,
                                                      const float* __restrict__ dis,
                                                      const float* __restrict__ b2,
                                                      const int* __restrict__ batch,
                                                      float* __restrict__ pooled,
                                                      const int* __restrict__ gstart,
                                                      int* __restrict__ done,
                                                      float* __restrict__ out) {
    __shared__ float vals[16][16];
    __shared__ int gid[16];
    __shared__ uint_t ecsr[A2CAP];       // 8192 B
    __shared__ int amlast;
    int wave = threadIdx.x >> 6, lane = threadIdx.x & 63;
    int node0 = blockIdx.x * 16;
    int node = node0 + wave;
    int slot = lane >> 3, sub = lane & 7;
    int wbeg = rowptr[node0];
    int wcap = rowptr[node0 + 16];
    int e0 = rowptr[node], e1 = rowptr[node + 1];
    float dn = dis[node];                // hoisted
    int   bg = batch[node];              // hoisted
    float b20 = b2[2 * sub], b21 = b2[2 * sub + 1];   // hoisted
    int wlen = min(wcap - wbeg, A2CAP);
    for (int i = threadIdx.x; i < wlen; i += 1024) ecsr[i] = csr[wbeg + i];
    __syncthreads();
    int wend = wbeg + wlen;

    float a0 = 0.0f, a1 = 0.0f;
    for (int e = e0 + slot; e < e1; e += 16) {
        uint_t ent0;
        if (e < wend) ent0 = ecsr[e - wbeg]; else ent0 = csr[e];
        bool has2 = (e + 8) < e1;
        uint_t ent1 = ent0;
        if (has2) {
            if (e + 8 < wend) ent1 = ecsr[e + 8 - wbeg]; else ent1 = csr[e + 8];
        }
        uint_t p0 = *(const uint_t*)(h2b + (size_t)(ent0 & 0xFFFFu) * CC + sub * 2);
        uint_t p1 = has2 ? *(const uint_t*)(h2b + (size_t)(ent1 & 0xFFFFu) * CC + sub * 2) : 0;
        float w0 = h2f((ushort_t)(ent0 >> 16));
        a0 += w0 * bf2f((ushort_t)(p0 & 0xFFFFu));
        a1 += w0 * bf2f((ushort_t)(p0 >> 16));
        if (has2) {
            float w1 = h2f((ushort_t)(ent1 >> 16));
            a0 += w1 * bf2f((ushort_t)(p1 & 0xFFFFu));
            a1 += w1 * bf2f((ushort_t)(p1 >> 16));
        }
    }
    a0 += __shfl_xor(a0, 8); a0 += __shfl_xor(a0, 16); a0 += __shfl_xor(a0, 32);
    a1 += __shfl_xor(a1, 8); a1 += __shfl_xor(a1, 16); a1 += __shfl_xor(a1, 32);
    if (slot == 0) {
        vals[wave][2 * sub]     = a0 * dn + b20;
        vals[wave][2 * sub + 1] = a1 * dn + b21;
        if (sub == 0) gid[wave] = bg;
    }
    __syncthreads();
    if (threadIdx.x < 16) {            // walker for channel threadIdx.x
        int c = threadIdx.x;
        float run = 0.0f;
        for (int i = 0; i < 16; i++) {
            run += vals[i][c];
            if (i == 15 || gid[i + 1] != gid[i]) {
                atomicAdd(&pooled[gid[i] * CC + c], run);
                run = 0.0f;
            }
        }
    }
    __syncthreads();
    if (threadIdx.x == 0) {
        __threadfence();                           // publish pool atomics
        int old = atomicAdd(done, 1);
        amlast = (old == (int)gridDim.x - 1);
    }
    __syncthreads();
    if (amlast) {
        __threadfence();                           // acquire all pool atomics
        for (int idx = threadIdx.x; idx < GG * CC; idx += 1024) {
            int g = idx >> 4;
            float cntg = (float)(gstart[g + 1] - gstart[g]);
            float v = pooled[idx] / fmaxf(cntg, 1.0f);
            float m = v;
            for (int off = 8; off >= 1; off >>= 1) m = fmaxf(m, __shfl_xor(m, off, 16));
            float s = expf(v - m);
            for (int off = 8; off >= 1; off >>= 1) s += __shfl_xor(s, off, 16);
            out[idx] = v - m - logf(s);
        }
    }
}

extern "C" void kernel_launch(void* const* d_in, const int* in_sizes, int n_in,
                              void* d_out, int out_size, void* d_ws, size_t ws_size,
                              hipStream_t stream) {
    const float* x  = (const float*)d_in[0];
    const float* W1 = (const float*)d_in[1];
    const float* b1 = (const float*)d_in[2];
    const float* W2 = (const float*)d_in[3];
    const float* b2 = (const float*)d_in[4];
    const int* edge_src = (const int*)d_in[5];
    const int* edge_dst = (const int*)d_in[6];
    const int* batch    = (const int*)d_in[7];
    float* out = (float*)d_out;

    char* ws = (char*)d_ws;
    size_t off = 0;
    auto alloc = [&](size_t bytes) {
        void* p = ws + off;
        off += (bytes + 255) & ~size_t(255);
        return p;
    };
    int*   cnt     = (int*)  alloc(NN * 4);
    float* dis     = (float*)alloc(NN * 4);
    int*   rowptr  = (int*)  alloc((NN + 1) * 4);
    int*   seq     = (int*)  alloc(EE * 4);
    uint_t* csr    = (uint_t*)alloc((size_t)ETOT * 4);
    unsigned char* hb8 = (unsigned char*)alloc((size_t)NN * HH);
    ushort_t* h2b  = (ushort_t*)alloc((size_t)NN * CC * 2);
    float* pooled  = (float*)alloc(GG * CC * 4);
    int*   gstart  = (int*)  alloc((GG + 1) * 4);
    int*   done    = (int*)  alloc(256);

    const int B = 256;
    init_kernel<<<(NN + B - 1) / B, B, 0, stream>>>(cnt, done);
    cg1_kernel<<<CBLK + (NN + 63) / 64, B, 0, stream>>>(edge_dst, cnt, seq, x, W1, hb8);
    scanF_kernel<<<1, 1024, 0, stream>>>(cnt, rowptr, dis, batch, gstart, pooled);
    fill_kernel<<<(ETOT + B - 1) / B, B, 0, stream>>>(edge_src, edge_dst, dis,
                                                      rowptr, seq, csr);
    agg1f_kernel<<<NN / 4, B, 0, stream>>>(hb8, rowptr, csr, dis, b1, W2, h2b);
    agg2pl_kernel<<<NN / 16, 1024, 0, stream>>>(h2b, rowptr, csr, dis, b2, batch,
                                                pooled, gstart, done, out);
}

// Round 7
// 253.511 us; speedup vs baseline: 1.7798x; 1.7798x over previous
//
#include <hip/hip_runtime.h>
#include <hip/hip_bf16.h>

// GCN 2-layer + mean-pool + log_softmax on gfx950.
// R17: revert R16's single-block scanF (230us disaster: 1 CU, 49 serial
//      loads/thread, VALUBusy 0.02% -- latency-serial on one CU) back to the
//      proven 196-block scanA + scanBC pair. Keep R16's other two changes:
//      lsm folded into agg2pl via completion ticket, and agg1f
//      __launch_bounds__(256,4) VGPR probe. 7 dispatches.

#define NN 50000
#define EE 600000
#define FIN 128
#define HH 128
#define CC 16
#define GG 500
#define ETOT (EE + NN)   // 650000
#define SBLK 196         // ceil(NN/256) scan blocks
#define WTS 140          // gemm1 wt row stride
#define CBLK ((EE + 255) / 256)   // 2344 count blocks in fused cg1
#define A1CAP 1024       // agg1f block csr window (4 nodes)
#define A2CAP 2048       // agg2pool block csr window (16 nodes)

typedef unsigned short ushort_t;
typedef unsigned int uint_t;

typedef __attribute__((ext_vector_type(8))) short bf16x8;
typedef __attribute__((ext_vector_type(4))) ushort_t u16x4;
typedef __attribute__((ext_vector_type(4))) float f32x4;
typedef __attribute__((ext_vector_type(2))) float f32x2;

__device__ inline ushort_t f2bf(float f) {
    uint_t u = __float_as_uint(f);
    u = (u + 0x7FFFu + ((u >> 16) & 1u)) >> 16;   // RNE
    return (ushort_t)u;
}
__device__ inline float bf2f(ushort_t b) {
    return __uint_as_float(((uint_t)b) << 16);
}
__device__ inline ushort_t f2h(float f) {
    _Float16 h = (_Float16)f; ushort_t u; __builtin_memcpy(&u, &h, 2); return u;
}
__device__ inline float h2f(ushort_t u) {
    _Float16 h; __builtin_memcpy(&h, &u, 2); return (float)h;
}

// ---------------- init: cnt + pooled + done ticket ----------------
__global__ void init_kernel(int* cnt, float* pooled, int* done) {
    int i = blockIdx.x * blockDim.x + threadIdx.x;
    if (i < NN) cnt[i] = 0;
    if (i < GG * CC) pooled[i] = 0.0f;
    if (i == 0) *done = 0;
}

// ---------------- fused count + GEMM1 ----------------------------------------
// blocks [0, CBLK): seq[e] = atomicAdd(&cnt[dst], 1)  (memory-side atomics,
//   latency-bound). blocks [CBLK, ...): hb8 = fp8(x @ W1) overlapping the
//   atomic tail on otherwise-idle VALU/MFMA pipes.
__global__ __launch_bounds__(256) void cg1_kernel(const int* __restrict__ edge_dst,
                                                  int* __restrict__ cnt,
                                                  int* __restrict__ seq,
                                                  const float* __restrict__ x,
                                                  const float* __restrict__ W1,
                                                  unsigned char* __restrict__ hb8) {
    __shared__ ushort_t xs[64 * 136];
    __shared__ ushort_t wt[128 * WTS];
    if (blockIdx.x < CBLK) {
        int idx = blockIdx.x * 256 + threadIdx.x;
        if (idx < EE) seq[idx] = atomicAdd(&cnt[edge_dst[idx]], 1);
        return;
    }
    int t = threadIdx.x;
    int row0 = (blockIdx.x - CBLK) * 64;
    for (int i = 0; i < 8; i++) {
        int slot = t + i * 256;
        int r = slot >> 5, k4 = slot & 31;
        int gr = row0 + r;
        float4 v = (gr < NN) ? ((const float4*)x)[gr * 32 + k4]
                             : make_float4(0.f, 0.f, 0.f, 0.f);
        u16x4 bv = { f2bf(v.x), f2bf(v.y), f2bf(v.z), f2bf(v.w) };
        *(u16x4*)(&xs[r * 136 + k4 * 4]) = bv;
    }
    for (int i = 0; i < 16; i++) {
        int idx = t + i * 256;
        int c = idx & 127, k4 = idx >> 7;
        u16x4 bv = { f2bf(W1[(4 * k4 + 0) * HH + c]),
                     f2bf(W1[(4 * k4 + 1) * HH + c]),
                     f2bf(W1[(4 * k4 + 2) * HH + c]),
                     f2bf(W1[(4 * k4 + 3) * HH + c]) };
        *(u16x4*)(&wt[c * WTS + k4 * 4]) = bv;
    }
    __syncthreads();

    int wave = t >> 6, lane = t & 63;
    int m = lane & 15, quad = lane >> 4;
    f32x4 acc[8];
    for (int ct = 0; ct < 8; ct++) acc[ct] = (f32x4)(0.0f);
    for (int ko = 0; ko < 4; ko++) {
        bf16x8 a = *(const bf16x8*)(&xs[(16 * wave + m) * 136 + ko * 32 + quad * 8]);
        for (int ct = 0; ct < 8; ct++) {
            bf16x8 b = *(const bf16x8*)(&wt[(ct * 16 + m) * WTS + ko * 32 + quad * 8]);
            acc[ct] = __builtin_amdgcn_mfma_f32_16x16x32_bf16(a, b, acc[ct], 0, 0, 0);
        }
    }
    for (int ct = 0; ct < 8; ct++) {
        int gcol = ct * 16 + m;
        for (int r = 0; r < 4; r++) {
            int grow = row0 + wave * 16 + quad * 4 + r;
            if (grow < NN) {
                int p = __builtin_amdgcn_cvt_pk_fp8_f32(acc[ct][r], 0.0f, 0, false);
                hb8[(size_t)grow * HH + gcol] = (unsigned char)(p & 0xFF);
            }
        }
    }
}

// ---------------- block-scan helper ----------------
__device__ inline int block_excl_scan(int v, int t, int* total) {
    __shared__ int wsum[4];
    int lane = t & 63, wv = t >> 6;
    int inc = v;
    for (int off = 1; off < 64; off <<= 1) {
        int n = __shfl_up(inc, off);
        if (lane >= off) inc += n;
    }
    if (lane == 63) wsum[wv] = inc;
    __syncthreads();
    int off_w = 0;
    for (int w = 0; w < wv; w++) off_w += wsum[w];
    *total = wsum[0] + wsum[1] + wsum[2] + wsum[3];
    return off_w + inc - v;
}

// ---------------- scan A (+ graph-boundary scatter, no atomics) ---------------
__global__ __launch_bounds__(256) void scanA_kernel(const int* __restrict__ cnt,
                                                    int* __restrict__ rowptr,
                                                    float* __restrict__ dis,
                                                    int* __restrict__ bsum,
                                                    const int* __restrict__ batch,
                                                    int* __restrict__ gstart) {
    int t = threadIdx.x;
    int i = blockIdx.x * 256 + t;
    int d = 0;
    if (i < NN) {
        d = cnt[i] + 1;                        // +1 self-loop
        dis[i] = rsqrtf((float)d);
        // batch is sorted: thread i owns boundaries (batch[i-1], batch[i]]
        int b = batch[i];
        int bp = (i == 0) ? -1 : batch[i - 1];
        for (int g = bp + 1; g <= b; ++g) gstart[g] = i;
        if (i == NN - 1) {
            for (int g = b + 1; g <= GG; ++g) gstart[g] = NN;
        }
    }
    int total;
    int excl = block_excl_scan(d, t, &total);
    if (i < NN) rowptr[i] = excl;
    if (t == 0) bsum[blockIdx.x] = total;
}

// ---------------- scan BC ----------------
__global__ __launch_bounds__(256) void scanBC_kernel(int* __restrict__ rowptr,
                                                     const int* __restrict__ bsum) {
    __shared__ int sb[256];
    int t = threadIdx.x;
    int v = (t < SBLK) ? bsum[t] : 0;
    int total;
    int ex = block_excl_scan(v, t, &total);
    sb[t] = ex;
    __syncthreads();
    int myoff = sb[blockIdx.x];
    int i = blockIdx.x * 256 + t;
    if (i < NN) rowptr[i] += myoff;
    if (blockIdx.x == 0 && t == 0) rowptr[NN] = ETOT;
}

// ---------------- CSR fill: entry = src | fp16(dis[src])<<16 ----------------
__global__ void fill_kernel(const int* __restrict__ edge_src,
                            const int* __restrict__ edge_dst,
                            const float* __restrict__ dis,
                            const int* __restrict__ rowptr,
                            const int* __restrict__ seq,
                            uint_t* __restrict__ csr) {
    int idx = blockIdx.x * blockDim.x + threadIdx.x;
    if (idx < EE) {
        int s = edge_src[idx], d = edge_dst[idx];
        csr[rowptr[d] + seq[idx]] = (uint_t)s | ((uint_t)f2h(dis[s]) << 16);
    } else if (idx < ETOT) {
        int n = idx - EE;
        csr[rowptr[n + 1] - 1] = (uint_t)n | ((uint_t)f2h(dis[n]) << 16);
    }
}

// ---------------- agg1 + in-LDS layer-2, LDS-staged csr window ----------------
// Gather structure = proven R10 (1 node/wave, 8 edge slots x 8 feature-lanes,
// 2-deep). Block csr window staged coalesced into LDS (cap + fallback). W2
// LDS table stride 132 (exact 2-per-bank, free). launch_bounds(256,4) lifts
// the compiler's 32-VGPR occupancy cap (probe: kernel pinned ~45us at VGPR=32
// across 4 structural variants).
__global__ __launch_bounds__(256, 4) void agg1f_kernel(const unsigned char* __restrict__ hb8,
                                                       const int* __restrict__ rowptr,
                                                       const uint_t* __restrict__ csr,
                                                       const float* __restrict__ dis,
                                                       const float* __restrict__ b1,
                                                       const float* __restrict__ W2,
                                                       ushort_t* __restrict__ h2b) {
    __shared__ uint_t w2s[8 * 132];      // 4224 B
    __shared__ uint_t ecsr[A1CAP];       // 4096 B
    int t = threadIdx.x;
    int node0 = blockIdx.x * 4;
    int wave = t >> 6, lane = t & 63;
    int node = node0 + wave;
    int slot = lane >> 3, sub = lane & 7;
    int wbeg = rowptr[node0];
    int wcap = rowptr[node0 + 4];
    int e0 = rowptr[node], e1 = rowptr[node + 1];
    float dn = dis[node];
    {
        const float2* W2v = (const float2*)W2;   // W2v[k*8+sl] = W2[k][2sl..2sl+1]
        for (int i = t; i < HH * 8; i += 256) {
            int k = i >> 3, sl = i & 7;
            float2 wv = W2v[i];
            w2s[(k >> 4) * 132 + (k & 15) * 8 + sl] =
                (uint_t)f2bf(wv.x) | ((uint_t)f2bf(wv.y) << 16);
        }
    }
    int wlen = min(wcap - wbeg, A1CAP);
    for (int i = t; i < wlen; i += 256) ecsr[i] = csr[wbeg + i];
    __syncthreads();   // start-barrier: all waves arrive together (no skew)
    int wend = wbeg + wlen;

    float acc[16];
    for (int j = 0; j < 16; j++) acc[j] = 0.0f;
    for (int e = e0 + slot; e < e1; e += 16) {
        uint_t ent0;
        if (e < wend) ent0 = ecsr[e - wbeg]; else ent0 = csr[e];
        bool has2 = (e + 8) < e1;
        uint_t ent1 = ent0;
        if (has2) {
            if (e + 8 < wend) ent1 = ecsr[e + 8 - wbeg]; else ent1 = csr[e + 8];
        }
        uint4 hv0 = *(const uint4*)(hb8 + (size_t)(ent0 & 0xFFFFu) * HH + sub * 16);
        uint4 hv1 = has2 ? *(const uint4*)(hb8 + (size_t)(ent1 & 0xFFFFu) * HH + sub * 16)
                         : make_uint4(0, 0, 0, 0);
        float w0 = h2f((ushort_t)(ent0 >> 16));
        uint_t words0[4] = { hv0.x, hv0.y, hv0.z, hv0.w };
        for (int q = 0; q < 4; q++) {
            f32x2 lo = __builtin_amdgcn_cvt_pk_f32_fp8(words0[q], false);
            f32x2 hi = __builtin_amdgcn_cvt_pk_f32_fp8(words0[q], true);
            acc[q * 4 + 0] += w0 * lo[0];
            acc[q * 4 + 1] += w0 * lo[1];
            acc[q * 4 + 2] += w0 * hi[0];
            acc[q * 4 + 3] += w0 * hi[1];
        }
        if (has2) {
            float w1 = h2f((ushort_t)(ent1 >> 16));
            uint_t words1[4] = { hv1.x, hv1.y, hv1.z, hv1.w };
            for (int q = 0; q < 4; q++) {
                f32x2 lo = __builtin_amdgcn_cvt_pk_f32_fp8(words1[q], false);
                f32x2 hi = __builtin_amdgcn_cvt_pk_f32_fp8(words1[q], true);
                acc[q * 4 + 0] += w1 * lo[0];
                acc[q * 4 + 1] += w1 * lo[1];
                acc[q * 4 + 2] += w1 * hi[0];
                acc[q * 4 + 3] += w1 * hi[1];
            }
        }
    }
    for (int j = 0; j < 16; j++) {
        acc[j] += __shfl_xor(acc[j], 8);
        acc[j] += __shfl_xor(acc[j], 16);
        acc[j] += __shfl_xor(acc[j], 32);
    }
    const float4* b1v = (const float4*)(b1 + sub * 16);
    float4 bb[4] = { b1v[0], b1v[1], b1v[2], b1v[3] };
    const float* bbf = (const float*)bb;
    float p0 = 0.0f, p1 = 0.0f;
    int wbase = sub * 132 + slot;
    for (int j = 0; j < 16; j++) {
        float h = fmaxf(dn * acc[j] + bbf[j], 0.0f);
        uint_t w = w2s[wbase + j * 8];
        p0 += h * __uint_as_float(w << 16);            // W2[sub*16+j][2slot]
        p1 += h * __uint_as_float(w & 0xFFFF0000u);    // W2[sub*16+j][2slot+1]
    }
    p0 += __shfl_xor(p0, 1); p0 += __shfl_xor(p0, 2); p0 += __shfl_xor(p0, 4);
    p1 += __shfl_xor(p1, 1); p1 += __shfl_xor(p1, 2); p1 += __shfl_xor(p1, 4);
    if (sub == 0) {
        uint_t pk = (uint_t)f2bf(p0) | ((uint_t)f2bf(p1) << 16);
        *(uint_t*)(h2b + (size_t)node * CC + 2 * slot) = pk;
    }
}

// ---------------- agg2 + pool + log_softmax (completion ticket) ---------------
// 1 node/wave, 16 nodes/block (1024 thr), LDS-staged csr window. After the
// pool atomics, last finishing block (device-scope ticket) computes the
// mean + log_softmax for all 500 graphs.
__global__ __launch_bounds__(1024) void agg2pl_kernel(const ushort_t* __restrict__ h2b,
                                                      const int* __restrict__ rowptr,
                                                      const uint_t* __restrict__ csr,
                                                      const float* __restrict__ dis,
                                                      const float* __restrict__ b2,
                                                      const int* __restrict__ batch,
                                                      float* __restrict__ pooled,
                                                      const int* __restrict__ gstart,
                                                      int* __restrict__ done,
                                                      float* __restrict__ out) {
    __shared__ float vals[16][16];
    __shared__ int gid[16];
    __shared__ uint_t ecsr[A2CAP];       // 8192 B
    __shared__ int amlast;
    int wave = threadIdx.x >> 6, lane = threadIdx.x & 63;
    int node0 = blockIdx.x * 16;
    int node = node0 + wave;
    int slot = lane >> 3, sub = lane & 7;
    int wbeg = rowptr[node0];
    int wcap = rowptr[node0 + 16];
    int e0 = rowptr[node], e1 = rowptr[node + 1];
    float dn = dis[node];                // hoisted
    int   bg = batch[node];              // hoisted
    float b20 = b2[2 * sub], b21 = b2[2 * sub + 1];   // hoisted
    int wlen = min(wcap - wbeg, A2CAP);
    for (int i = threadIdx.x; i < wlen; i += 1024) ecsr[i] = csr[wbeg + i];
    __syncthreads();
    int wend = wbeg + wlen;

    float a0 = 0.0f, a1 = 0.0f;
    for (int e = e0 + slot; e < e1; e += 16) {
        uint_t ent0;
        if (e < wend) ent0 = ecsr[e - wbeg]; else ent0 = csr[e];
        bool has2 = (e + 8) < e1;
        uint_t ent1 = ent0;
        if (has2) {
            if (e + 8 < wend) ent1 = ecsr[e + 8 - wbeg]; else ent1 = csr[e + 8];
        }
        uint_t p0 = *(const uint_t*)(h2b + (size_t)(ent0 & 0xFFFFu) * CC + sub * 2);
        uint_t p1 = has2 ? *(const uint_t*)(h2b + (size_t)(ent1 & 0xFFFFu) * CC + sub * 2) : 0;
        float w0 = h2f((ushort_t)(ent0 >> 16));
        a0 += w0 * bf2f((ushort_t)(p0 & 0xFFFFu));
        a1 += w0 * bf2f((ushort_t)(p0 >> 16));
        if (has2) {
            float w1 = h2f((ushort_t)(ent1 >> 16));
            a0 += w1 * bf2f((ushort_t)(p1 & 0xFFFFu));
            a1 += w1 * bf2f((ushort_t)(p1 >> 16));
        }
    }
    a0 += __shfl_xor(a0, 8); a0 += __shfl_xor(a0, 16); a0 += __shfl_xor(a0, 32);
    a1 += __shfl_xor(a1, 8); a1 += __shfl_xor(a1, 16); a1 += __shfl_xor(a1, 32);
    if (slot == 0) {
        vals[wave][2 * sub]     = a0 * dn + b20;
        vals[wave][2 * sub + 1] = a1 * dn + b21;
        if (sub == 0) gid[wave] = bg;
    }
    __syncthreads();
    if (threadIdx.x < 16) {            // walker for channel threadIdx.x
        int c = threadIdx.x;
        float run = 0.0f;
        for (int i = 0; i < 16; i++) {
            run += vals[i][c];
            if (i == 15 || gid[i + 1] != gid[i]) {
                atomicAdd(&pooled[gid[i] * CC + c], run);
                run = 0.0f;
            }
        }
    }
    __syncthreads();
    if (threadIdx.x == 0) {
        __threadfence();                           // publish pool atomics
        int old = atomicAdd(done, 1);
        amlast = (old == (int)gridDim.x - 1);
    }
    __syncthreads();
    if (amlast) {
        __threadfence();                           // acquire all pool atomics
        for (int idx = threadIdx.x; idx < GG * CC; idx += 1024) {
            int g = idx >> 4;
            float cntg = (float)(gstart[g + 1] - gstart[g]);
            float v = pooled[idx] / fmaxf(cntg, 1.0f);
            float m = v;
            for (int off = 8; off >= 1; off >>= 1) m = fmaxf(m, __shfl_xor(m, off, 16));
            float s = expf(v - m);
            for (int off = 8; off >= 1; off >>= 1) s += __shfl_xor(s, off, 16);
            out[idx] = v - m - logf(s);
        }
    }
}

extern "C" void kernel_launch(void* const* d_in, const int* in_sizes, int n_in,
                              void* d_out, int out_size, void* d_ws, size_t ws_size,
                              hipStream_t stream) {
    const float* x  = (const float*)d_in[0];
    const float* W1 = (const float*)d_in[1];
    const float* b1 = (const float*)d_in[2];
    const float* W2 = (const float*)d_in[3];
    const float* b2 = (const float*)d_in[4];
    const int* edge_src = (const int*)d_in[5];
    const int* edge_dst = (const int*)d_in[6];
    const int* batch    = (const int*)d_in[7];
    float* out = (float*)d_out;

    char* ws = (char*)d_ws;
    size_t off = 0;
    auto alloc = [&](size_t bytes) {
        void* p = ws + off;
        off += (bytes + 255) & ~size_t(255);
        return p;
    };
    int*   cnt     = (int*)  alloc(NN * 4);
    float* dis     = (float*)alloc(NN * 4);
    int*   rowptr  = (int*)  alloc((NN + 1) * 4);
    int*   seq     = (int*)  alloc(EE * 4);
    int*   bsum    = (int*)  alloc(SBLK * 4);
    uint_t* csr    = (uint_t*)alloc((size_t)ETOT * 4);
    unsigned char* hb8 = (unsigned char*)alloc((size_t)NN * HH);
    ushort_t* h2b  = (ushort_t*)alloc((size_t)NN * CC * 2);
    float* pooled  = (float*)alloc(GG * CC * 4);
    int*   gstart  = (int*)  alloc((GG + 1) * 4);
    int*   done    = (int*)  alloc(256);

    const int B = 256;
    init_kernel<<<(NN + B - 1) / B, B, 0, stream>>>(cnt, pooled, done);
    cg1_kernel<<<CBLK + (NN + 63) / 64, B, 0, stream>>>(edge_dst, cnt, seq, x, W1, hb8);
    scanA_kernel<<<SBLK, B, 0, stream>>>(cnt, rowptr, dis, bsum, batch, gstart);
    scanBC_kernel<<<SBLK, B, 0, stream>>>(rowptr, bsum);
    fill_kernel<<<(ETOT + B - 1) / B, B, 0, stream>>>(edge_src, edge_dst, dis,
                                                      rowptr, seq, csr);
    agg1f_kernel<<<NN / 4, B, 0, stream>>>(hb8, rowptr, csr, dis, b1, W2, h2b);
    agg2pl_kernel<<<NN / 16, 1024, 0, stream>>>(h2b, rowptr, csr, dis, b2, batch,
                                                pooled, gstart, done, out);
}

// Round 8
// 196.381 us; speedup vs baseline: 2.2976x; 1.2909x over previous
//
#include <hip/hip_runtime.h>
#include <hip/hip_bf16.h>

// GCN 2-layer + mean-pool + log_softmax on gfx950.
// R18: revert R17's lsm-in-agg2pool completion ticket. The per-block
//      __threadfence() (L2 writeback on non-coherent XCD L2s) + the VGPR=16
//      heuristic collapse turned an ~18us kernel into 81us. Back to R15's
//      proven agg2pool + standalone lsm (8 dispatches). Keep agg1f
//      __launch_bounds__(256,4) probe (clean A/B this round). Third data
//      point on the rule: never graft sync-bearing tails onto proven
//      latency-bound gather kernels.

#define NN 50000
#define EE 600000
#define FIN 128
#define HH 128
#define CC 16
#define GG 500
#define ETOT (EE + NN)   // 650000
#define SBLK 196         // ceil(NN/256) scan blocks
#define WTS 140          // gemm1 wt row stride
#define CBLK ((EE + 255) / 256)   // 2344 count blocks in fused cg1
#define A1CAP 1024       // agg1f block csr window (4 nodes)
#define A2CAP 2048       // agg2pool block csr window (16 nodes)

typedef unsigned short ushort_t;
typedef unsigned int uint_t;

typedef __attribute__((ext_vector_type(8))) short bf16x8;
typedef __attribute__((ext_vector_type(4))) ushort_t u16x4;
typedef __attribute__((ext_vector_type(4))) float f32x4;
typedef __attribute__((ext_vector_type(2))) float f32x2;

__device__ inline ushort_t f2bf(float f) {
    uint_t u = __float_as_uint(f);
    u = (u + 0x7FFFu + ((u >> 16) & 1u)) >> 16;   // RNE
    return (ushort_t)u;
}
__device__ inline float bf2f(ushort_t b) {
    return __uint_as_float(((uint_t)b) << 16);
}
__device__ inline ushort_t f2h(float f) {
    _Float16 h = (_Float16)f; ushort_t u; __builtin_memcpy(&u, &h, 2); return u;
}
__device__ inline float h2f(ushort_t u) {
    _Float16 h; __builtin_memcpy(&h, &u, 2); return (float)h;
}

// ---------------- init: cnt + pooled ----------------
__global__ void init_kernel(int* cnt, float* pooled) {
    int i = blockIdx.x * blockDim.x + threadIdx.x;
    if (i < NN) cnt[i] = 0;
    if (i < GG * CC) pooled[i] = 0.0f;
}

// ---------------- fused count + GEMM1 ----------------------------------------
// blocks [0, CBLK): seq[e] = atomicAdd(&cnt[dst], 1)  (memory-side atomics,
//   latency-bound). blocks [CBLK, ...): hb8 = fp8(x @ W1) overlapping the
//   atomic tail on otherwise-idle VALU/MFMA pipes.
__global__ __launch_bounds__(256) void cg1_kernel(const int* __restrict__ edge_dst,
                                                  int* __restrict__ cnt,
                                                  int* __restrict__ seq,
                                                  const float* __restrict__ x,
                                                  const float* __restrict__ W1,
                                                  unsigned char* __restrict__ hb8) {
    __shared__ ushort_t xs[64 * 136];
    __shared__ ushort_t wt[128 * WTS];
    if (blockIdx.x < CBLK) {
        int idx = blockIdx.x * 256 + threadIdx.x;
        if (idx < EE) seq[idx] = atomicAdd(&cnt[edge_dst[idx]], 1);
        return;
    }
    int t = threadIdx.x;
    int row0 = (blockIdx.x - CBLK) * 64;
    for (int i = 0; i < 8; i++) {
        int slot = t + i * 256;
        int r = slot >> 5, k4 = slot & 31;
        int gr = row0 + r;
        float4 v = (gr < NN) ? ((const float4*)x)[gr * 32 + k4]
                             : make_float4(0.f, 0.f, 0.f, 0.f);
        u16x4 bv = { f2bf(v.x), f2bf(v.y), f2bf(v.z), f2bf(v.w) };
        *(u16x4*)(&xs[r * 136 + k4 * 4]) = bv;
    }
    for (int i = 0; i < 16; i++) {
        int idx = t + i * 256;
        int c = idx & 127, k4 = idx >> 7;
        u16x4 bv = { f2bf(W1[(4 * k4 + 0) * HH + c]),
                     f2bf(W1[(4 * k4 + 1) * HH + c]),
                     f2bf(W1[(4 * k4 + 2) * HH + c]),
                     f2bf(W1[(4 * k4 + 3) * HH + c]) };
        *(u16x4*)(&wt[c * WTS + k4 * 4]) = bv;
    }
    __syncthreads();

    int wave = t >> 6, lane = t & 63;
    int m = lane & 15, quad = lane >> 4;
    f32x4 acc[8];
    for (int ct = 0; ct < 8; ct++) acc[ct] = (f32x4)(0.0f);
    for (int ko = 0; ko < 4; ko++) {
        bf16x8 a = *(const bf16x8*)(&xs[(16 * wave + m) * 136 + ko * 32 + quad * 8]);
        for (int ct = 0; ct < 8; ct++) {
            bf16x8 b = *(const bf16x8*)(&wt[(ct * 16 + m) * WTS + ko * 32 + quad * 8]);
            acc[ct] = __builtin_amdgcn_mfma_f32_16x16x32_bf16(a, b, acc[ct], 0, 0, 0);
        }
    }
    for (int ct = 0; ct < 8; ct++) {
        int gcol = ct * 16 + m;
        for (int r = 0; r < 4; r++) {
            int grow = row0 + wave * 16 + quad * 4 + r;
            if (grow < NN) {
                int p = __builtin_amdgcn_cvt_pk_fp8_f32(acc[ct][r], 0.0f, 0, false);
                hb8[(size_t)grow * HH + gcol] = (unsigned char)(p & 0xFF);
            }
        }
    }
}

// ---------------- block-scan helper ----------------
__device__ inline int block_excl_scan(int v, int t, int* total) {
    __shared__ int wsum[4];
    int lane = t & 63, wv = t >> 6;
    int inc = v;
    for (int off = 1; off < 64; off <<= 1) {
        int n = __shfl_up(inc, off);
        if (lane >= off) inc += n;
    }
    if (lane == 63) wsum[wv] = inc;
    __syncthreads();
    int off_w = 0;
    for (int w = 0; w < wv; w++) off_w += wsum[w];
    *total = wsum[0] + wsum[1] + wsum[2] + wsum[3];
    return off_w + inc - v;
}

// ---------------- scan A (+ graph-boundary scatter, no atomics) ---------------
__global__ __launch_bounds__(256) void scanA_kernel(const int* __restrict__ cnt,
                                                    int* __restrict__ rowptr,
                                                    float* __restrict__ dis,
                                                    int* __restrict__ bsum,
                                                    const int* __restrict__ batch,
                                                    int* __restrict__ gstart) {
    int t = threadIdx.x;
    int i = blockIdx.x * 256 + t;
    int d = 0;
    if (i < NN) {
        d = cnt[i] + 1;                        // +1 self-loop
        dis[i] = rsqrtf((float)d);
        // batch is sorted: thread i owns boundaries (batch[i-1], batch[i]]
        int b = batch[i];
        int bp = (i == 0) ? -1 : batch[i - 1];
        for (int g = bp + 1; g <= b; ++g) gstart[g] = i;
        if (i == NN - 1) {
            for (int g = b + 1; g <= GG; ++g) gstart[g] = NN;
        }
    }
    int total;
    int excl = block_excl_scan(d, t, &total);
    if (i < NN) rowptr[i] = excl;
    if (t == 0) bsum[blockIdx.x] = total;
}

// ---------------- scan BC ----------------
__global__ __launch_bounds__(256) void scanBC_kernel(int* __restrict__ rowptr,
                                                     const int* __restrict__ bsum) {
    __shared__ int sb[256];
    int t = threadIdx.x;
    int v = (t < SBLK) ? bsum[t] : 0;
    int total;
    int ex = block_excl_scan(v, t, &total);
    sb[t] = ex;
    __syncthreads();
    int myoff = sb[blockIdx.x];
    int i = blockIdx.x * 256 + t;
    if (i < NN) rowptr[i] += myoff;
    if (blockIdx.x == 0 && t == 0) rowptr[NN] = ETOT;
}

// ---------------- CSR fill: entry = src | fp16(dis[src])<<16 ----------------
__global__ void fill_kernel(const int* __restrict__ edge_src,
                            const int* __restrict__ edge_dst,
                            const float* __restrict__ dis,
                            const int* __restrict__ rowptr,
                            const int* __restrict__ seq,
                            uint_t* __restrict__ csr) {
    int idx = blockIdx.x * blockDim.x + threadIdx.x;
    if (idx < EE) {
        int s = edge_src[idx], d = edge_dst[idx];
        csr[rowptr[d] + seq[idx]] = (uint_t)s | ((uint_t)f2h(dis[s]) << 16);
    } else if (idx < ETOT) {
        int n = idx - EE;
        csr[rowptr[n + 1] - 1] = (uint_t)n | ((uint_t)f2h(dis[n]) << 16);
    }
}

// ---------------- agg1 + in-LDS layer-2, LDS-staged csr window ----------------
// Gather structure = proven R10 (1 node/wave, 8 edge slots x 8 feature-lanes,
// 2-deep). Block csr window staged coalesced into LDS (cap + fallback). W2
// LDS table stride 132 (exact 2-per-bank, free). launch_bounds(256,4) lifts
// the compiler's 32-VGPR occupancy cap.
__global__ __launch_bounds__(256, 4) void agg1f_kernel(const unsigned char* __restrict__ hb8,
                                                       const int* __restrict__ rowptr,
                                                       const uint_t* __restrict__ csr,
                                                       const float* __restrict__ dis,
                                                       const float* __restrict__ b1,
                                                       const float* __restrict__ W2,
                                                       ushort_t* __restrict__ h2b) {
    __shared__ uint_t w2s[8 * 132];      // 4224 B
    __shared__ uint_t ecsr[A1CAP];       // 4096 B
    int t = threadIdx.x;
    int node0 = blockIdx.x * 4;
    int wave = t >> 6, lane = t & 63;
    int node = node0 + wave;
    int slot = lane >> 3, sub = lane & 7;
    int wbeg = rowptr[node0];
    int wcap = rowptr[node0 + 4];
    int e0 = rowptr[node], e1 = rowptr[node + 1];
    float dn = dis[node];
    {
        const float2* W2v = (const float2*)W2;   // W2v[k*8+sl] = W2[k][2sl..2sl+1]
        for (int i = t; i < HH * 8; i += 256) {
            int k = i >> 3, sl = i & 7;
            float2 wv = W2v[i];
            w2s[(k >> 4) * 132 + (k & 15) * 8 + sl] =
                (uint_t)f2bf(wv.x) | ((uint_t)f2bf(wv.y) << 16);
        }
    }
    int wlen = min(wcap - wbeg, A1CAP);
    for (int i = t; i < wlen; i += 256) ecsr[i] = csr[wbeg + i];
    __syncthreads();   // start-barrier: all waves arrive together (no skew)
    int wend = wbeg + wlen;

    float acc[16];
    for (int j = 0; j < 16; j++) acc[j] = 0.0f;
    for (int e = e0 + slot; e < e1; e += 16) {
        uint_t ent0;
        if (e < wend) ent0 = ecsr[e - wbeg]; else ent0 = csr[e];
        bool has2 = (e + 8) < e1;
        uint_t ent1 = ent0;
        if (has2) {
            if (e + 8 < wend) ent1 = ecsr[e + 8 - wbeg]; else ent1 = csr[e + 8];
        }
        uint4 hv0 = *(const uint4*)(hb8 + (size_t)(ent0 & 0xFFFFu) * HH + sub * 16);
        uint4 hv1 = has2 ? *(const uint4*)(hb8 + (size_t)(ent1 & 0xFFFFu) * HH + sub * 16)
                         : make_uint4(0, 0, 0, 0);
        float w0 = h2f((ushort_t)(ent0 >> 16));
        uint_t words0[4] = { hv0.x, hv0.y, hv0.z, hv0.w };
        for (int q = 0; q < 4; q++) {
            f32x2 lo = __builtin_amdgcn_cvt_pk_f32_fp8(words0[q], false);
            f32x2 hi = __builtin_amdgcn_cvt_pk_f32_fp8(words0[q], true);
            acc[q * 4 + 0] += w0 * lo[0];
            acc[q * 4 + 1] += w0 * lo[1];
            acc[q * 4 + 2] += w0 * hi[0];
            acc[q * 4 + 3] += w0 * hi[1];
        }
        if (has2) {
            float w1 = h2f((ushort_t)(ent1 >> 16));
            uint_t words1[4] = { hv1.x, hv1.y, hv1.z, hv1.w };
            for (int q = 0; q < 4; q++) {
                f32x2 lo = __builtin_amdgcn_cvt_pk_f32_fp8(words1[q], false);
                f32x2 hi = __builtin_amdgcn_cvt_pk_f32_fp8(words1[q], true);
                acc[q * 4 + 0] += w1 * lo[0];
                acc[q * 4 + 1] += w1 * lo[1];
                acc[q * 4 + 2] += w1 * hi[0];
                acc[q * 4 + 3] += w1 * hi[1];
            }
        }
    }
    for (int j = 0; j < 16; j++) {
        acc[j] += __shfl_xor(acc[j], 8);
        acc[j] += __shfl_xor(acc[j], 16);
        acc[j] += __shfl_xor(acc[j], 32);
    }
    const float4* b1v = (const float4*)(b1 + sub * 16);
    float4 bb[4] = { b1v[0], b1v[1], b1v[2], b1v[3] };
    const float* bbf = (const float*)bb;
    float p0 = 0.0f, p1 = 0.0f;
    int wbase = sub * 132 + slot;
    for (int j = 0; j < 16; j++) {
        float h = fmaxf(dn * acc[j] + bbf[j], 0.0f);
        uint_t w = w2s[wbase + j * 8];
        p0 += h * __uint_as_float(w << 16);            // W2[sub*16+j][2slot]
        p1 += h * __uint_as_float(w & 0xFFFF0000u);    // W2[sub*16+j][2slot+1]
    }
    p0 += __shfl_xor(p0, 1); p0 += __shfl_xor(p0, 2); p0 += __shfl_xor(p0, 4);
    p1 += __shfl_xor(p1, 1); p1 += __shfl_xor(p1, 2); p1 += __shfl_xor(p1, 4);
    if (sub == 0) {
        uint_t pk = (uint_t)f2bf(p0) | ((uint_t)f2bf(p1) << 16);
        *(uint_t*)(h2b + (size_t)node * CC + 2 * slot) = pk;
    }
}

// ---------------- agg2 + pool: LDS-staged csr window (R15 proven) -------------
__global__ __launch_bounds__(1024) void agg2pool_kernel(const ushort_t* __restrict__ h2b,
                                                        const int* __restrict__ rowptr,
                                                        const uint_t* __restrict__ csr,
                                                        const float* __restrict__ dis,
                                                        const float* __restrict__ b2,
                                                        const int* __restrict__ batch,
                                                        float* __restrict__ pooled) {
    __shared__ float vals[16][16];
    __shared__ int gid[16];
    __shared__ uint_t ecsr[A2CAP];       // 8192 B
    int wave = threadIdx.x >> 6, lane = threadIdx.x & 63;
    int node0 = blockIdx.x * 16;
    int node = node0 + wave;
    int slot = lane >> 3, sub = lane & 7;
    int wbeg = rowptr[node0];
    int wcap = rowptr[node0 + 16];
    int e0 = rowptr[node], e1 = rowptr[node + 1];
    float dn = dis[node];                // hoisted
    int   bg = batch[node];              // hoisted
    float b20 = b2[2 * sub], b21 = b2[2 * sub + 1];   // hoisted
    int wlen = min(wcap - wbeg, A2CAP);
    for (int i = threadIdx.x; i < wlen; i += 1024) ecsr[i] = csr[wbeg + i];
    __syncthreads();
    int wend = wbeg + wlen;

    float a0 = 0.0f, a1 = 0.0f;
    for (int e = e0 + slot; e < e1; e += 16) {
        uint_t ent0;
        if (e < wend) ent0 = ecsr[e - wbeg]; else ent0 = csr[e];
        bool has2 = (e + 8) < e1;
        uint_t ent1 = ent0;
        if (has2) {
            if (e + 8 < wend) ent1 = ecsr[e + 8 - wbeg]; else ent1 = csr[e + 8];
        }
        uint_t p0 = *(const uint_t*)(h2b + (size_t)(ent0 & 0xFFFFu) * CC + sub * 2);
        uint_t p1 = has2 ? *(const uint_t*)(h2b + (size_t)(ent1 & 0xFFFFu) * CC + sub * 2) : 0;
        float w0 = h2f((ushort_t)(ent0 >> 16));
        a0 += w0 * bf2f((ushort_t)(p0 & 0xFFFFu));
        a1 += w0 * bf2f((ushort_t)(p0 >> 16));
        if (has2) {
            float w1 = h2f((ushort_t)(ent1 >> 16));
            a0 += w1 * bf2f((ushort_t)(p1 & 0xFFFFu));
            a1 += w1 * bf2f((ushort_t)(p1 >> 16));
        }
    }
    a0 += __shfl_xor(a0, 8); a0 += __shfl_xor(a0, 16); a0 += __shfl_xor(a0, 32);
    a1 += __shfl_xor(a1, 8); a1 += __shfl_xor(a1, 16); a1 += __shfl_xor(a1, 32);
    if (slot == 0) {
        vals[wave][2 * sub]     = a0 * dn + b20;
        vals[wave][2 * sub + 1] = a1 * dn + b21;
        if (sub == 0) gid[wave] = bg;
    }
    __syncthreads();
    if (threadIdx.x < 16) {            // walker for channel threadIdx.x
        int c = threadIdx.x;
        float run = 0.0f;
        for (int i = 0; i < 16; i++) {
            run += vals[i][c];
            if (i == 15 || gid[i + 1] != gid[i]) {
                atomicAdd(&pooled[gid[i] * CC + c], run);
                run = 0.0f;
            }
        }
    }
}

// ---------------- mean + log_softmax (counts from gstart) ---------------------
__global__ void lsm_kernel(const float* __restrict__ pooled,
                           const int* __restrict__ gstart,
                           float* __restrict__ out) {
    int idx = blockIdx.x * blockDim.x + threadIdx.x;
    int g = idx >> 4, c = idx & 15;
    if (g >= GG) return;
    float cnt = (float)(gstart[g + 1] - gstart[g]);
    float v = pooled[g * CC + c] / fmaxf(cnt, 1.0f);
    float m = v;
    for (int off = 8; off >= 1; off >>= 1) m = fmaxf(m, __shfl_xor(m, off, 16));
    float s = expf(v - m);
    for (int off = 8; off >= 1; off >>= 1) s += __shfl_xor(s, off, 16);
    out[g * CC + c] = v - m - logf(s);
}

extern "C" void kernel_launch(void* const* d_in, const int* in_sizes, int n_in,
                              void* d_out, int out_size, void* d_ws, size_t ws_size,
                              hipStream_t stream) {
    const float* x  = (const float*)d_in[0];
    const float* W1 = (const float*)d_in[1];
    const float* b1 = (const float*)d_in[2];
    const float* W2 = (const float*)d_in[3];
    const float* b2 = (const float*)d_in[4];
    const int* edge_src = (const int*)d_in[5];
    const int* edge_dst = (const int*)d_in[6];
    const int* batch    = (const int*)d_in[7];
    float* out = (float*)d_out;

    char* ws = (char*)d_ws;
    size_t off = 0;
    auto alloc = [&](size_t bytes) {
        void* p = ws + off;
        off += (bytes + 255) & ~size_t(255);
        return p;
    };
    int*   cnt     = (int*)  alloc(NN * 4);
    float* dis     = (float*)alloc(NN * 4);
    int*   rowptr  = (int*)  alloc((NN + 1) * 4);
    int*   seq     = (int*)  alloc(EE * 4);
    int*   bsum    = (int*)  alloc(SBLK * 4);
    uint_t* csr    = (uint_t*)alloc((size_t)ETOT * 4);
    unsigned char* hb8 = (unsigned char*)alloc((size_t)NN * HH);
    ushort_t* h2b  = (ushort_t*)alloc((size_t)NN * CC * 2);
    float* pooled  = (float*)alloc(GG * CC * 4);
    int*   gstart  = (int*)  alloc((GG + 1) * 4);

    const int B = 256;
    init_kernel<<<(NN + B - 1) / B, B, 0, stream>>>(cnt, pooled);
    cg1_kernel<<<CBLK + (NN + 63) / 64, B, 0, stream>>>(edge_dst, cnt, seq, x, W1, hb8);
    scanA_kernel<<<SBLK, B, 0, stream>>>(cnt, rowptr, dis, bsum, batch, gstart);
    scanBC_kernel<<<SBLK, B, 0, stream>>>(rowptr, bsum);
    fill_kernel<<<(ETOT + B - 1) / B, B, 0, stream>>>(edge_src, edge_dst, dis,
                                                      rowptr, seq, csr);
    agg1f_kernel<<<NN / 4, B, 0, stream>>>(hb8, rowptr, csr, dis, b1, W2, h2b);
    agg2pool_kernel<<<NN / 16, 1024, 0, stream>>>(h2b, rowptr, csr, dis, b2, batch, pooled);
    lsm_kernel<<<(GG * CC + B - 1) / B, B, 0, stream>>>(pooled, gstart, out);
}

// Round 9
// 194.214 us; speedup vs baseline: 2.3233x; 1.0112x over previous
//
#include <hip/hip_runtime.h>
#include <hip/hip_bf16.h>

// GCN 2-layer + mean-pool + log_softmax on gfx950.
// R19: two independent probes on the two 45us kernels.
//      (1) cnt padded to one counter per 64B line (cnt[dst*16]): the count
//          pass's 600K memory-side atomics currently hit 16 counters/line
//          (~192 serialized RMW/line); if serialization is per-line, padding
//          cuts it ~16x.
//      (2) agg1f inner loop accumulates into f32x2 pairs so cvt_pk_f32_fp8
//          output feeds v_pk_fma_f32 (CDNA4 packed dual FMA): 24 -> 16 VALU
//          ops per entry (kernel is 61% VALU-busy). Same registers, same
//          epilogue via float* cast.
//      VGPR-cap theory retired (VGPR=32 even under launch_bounds(256,4) ->
//      compiler genuinely needs 32). Everything else = R18 structure.

#define NN 50000
#define EE 600000
#define FIN 128
#define HH 128
#define CC 16
#define GG 500
#define ETOT (EE + NN)   // 650000
#define SBLK 196         // ceil(NN/256) scan blocks
#define WTS 140          // gemm1 wt row stride
#define CBLK ((EE + 255) / 256)   // 2344 count blocks in fused cg1
#define A1CAP 1024       // agg1f block csr window (4 nodes)
#define A2CAP 2048       // agg2pool block csr window (16 nodes)
#define CSTR 16          // cnt stride in ints (64B line per counter)

typedef unsigned short ushort_t;
typedef unsigned int uint_t;

typedef __attribute__((ext_vector_type(8))) short bf16x8;
typedef __attribute__((ext_vector_type(4))) ushort_t u16x4;
typedef __attribute__((ext_vector_type(4))) float f32x4;
typedef __attribute__((ext_vector_type(2))) float f32x2;

__device__ inline ushort_t f2bf(float f) {
    uint_t u = __float_as_uint(f);
    u = (u + 0x7FFFu + ((u >> 16) & 1u)) >> 16;   // RNE
    return (ushort_t)u;
}
__device__ inline float bf2f(ushort_t b) {
    return __uint_as_float(((uint_t)b) << 16);
}
__device__ inline ushort_t f2h(float f) {
    _Float16 h = (_Float16)f; ushort_t u; __builtin_memcpy(&u, &h, 2); return u;
}
__device__ inline float h2f(ushort_t u) {
    _Float16 h; __builtin_memcpy(&h, &u, 2); return (float)h;
}

// ---------------- init: cnt (padded) + pooled ----------------
__global__ void init_kernel(int* cnt, float* pooled) {
    int i = blockIdx.x * blockDim.x + threadIdx.x;
    if (i < NN * CSTR) cnt[i] = 0;
    if (i < GG * CC) pooled[i] = 0.0f;
}

// ---------------- fused count + GEMM1 ----------------------------------------
// blocks [0, CBLK): seq[e] = atomicAdd(&cnt[dst*CSTR], 1) - one counter per
//   64B line. blocks [CBLK, ...): hb8 = fp8(x @ W1) overlapping the atomic
//   tail on otherwise-idle VALU/MFMA pipes.
__global__ __launch_bounds__(256) void cg1_kernel(const int* __restrict__ edge_dst,
                                                  int* __restrict__ cnt,
                                                  int* __restrict__ seq,
                                                  const float* __restrict__ x,
                                                  const float* __restrict__ W1,
                                                  unsigned char* __restrict__ hb8) {
    __shared__ ushort_t xs[64 * 136];
    __shared__ ushort_t wt[128 * WTS];
    if (blockIdx.x < CBLK) {
        int idx = blockIdx.x * 256 + threadIdx.x;
        if (idx < EE) seq[idx] = atomicAdd(&cnt[edge_dst[idx] * CSTR], 1);
        return;
    }
    int t = threadIdx.x;
    int row0 = (blockIdx.x - CBLK) * 64;
    for (int i = 0; i < 8; i++) {
        int slot = t + i * 256;
        int r = slot >> 5, k4 = slot & 31;
        int gr = row0 + r;
        float4 v = (gr < NN) ? ((const float4*)x)[gr * 32 + k4]
                             : make_float4(0.f, 0.f, 0.f, 0.f);
        u16x4 bv = { f2bf(v.x), f2bf(v.y), f2bf(v.z), f2bf(v.w) };
        *(u16x4*)(&xs[r * 136 + k4 * 4]) = bv;
    }
    for (int i = 0; i < 16; i++) {
        int idx = t + i * 256;
        int c = idx & 127, k4 = idx >> 7;
        u16x4 bv = { f2bf(W1[(4 * k4 + 0) * HH + c]),
                     f2bf(W1[(4 * k4 + 1) * HH + c]),
                     f2bf(W1[(4 * k4 + 2) * HH + c]),
                     f2bf(W1[(4 * k4 + 3) * HH + c]) };
        *(u16x4*)(&wt[c * WTS + k4 * 4]) = bv;
    }
    __syncthreads();

    int wave = t >> 6, lane = t & 63;
    int m = lane & 15, quad = lane >> 4;
    f32x4 acc[8];
    for (int ct = 0; ct < 8; ct++) acc[ct] = (f32x4)(0.0f);
    for (int ko = 0; ko < 4; ko++) {
        bf16x8 a = *(const bf16x8*)(&xs[(16 * wave + m) * 136 + ko * 32 + quad * 8]);
        for (int ct = 0; ct < 8; ct++) {
            bf16x8 b = *(const bf16x8*)(&wt[(ct * 16 + m) * WTS + ko * 32 + quad * 8]);
            acc[ct] = __builtin_amdgcn_mfma_f32_16x16x32_bf16(a, b, acc[ct], 0, 0, 0);
        }
    }
    for (int ct = 0; ct < 8; ct++) {
        int gcol = ct * 16 + m;
        for (int r = 0; r < 4; r++) {
            int grow = row0 + wave * 16 + quad * 4 + r;
            if (grow < NN) {
                int p = __builtin_amdgcn_cvt_pk_fp8_f32(acc[ct][r], 0.0f, 0, false);
                hb8[(size_t)grow * HH + gcol] = (unsigned char)(p & 0xFF);
            }
        }
    }
}

// ---------------- block-scan helper ----------------
__device__ inline int block_excl_scan(int v, int t, int* total) {
    __shared__ int wsum[4];
    int lane = t & 63, wv = t >> 6;
    int inc = v;
    for (int off = 1; off < 64; off <<= 1) {
        int n = __shfl_up(inc, off);
        if (lane >= off) inc += n;
    }
    if (lane == 63) wsum[wv] = inc;
    __syncthreads();
    int off_w = 0;
    for (int w = 0; w < wv; w++) off_w += wsum[w];
    *total = wsum[0] + wsum[1] + wsum[2] + wsum[3];
    return off_w + inc - v;
}

// ---------------- scan A (+ graph-boundary scatter, no atomics) ---------------
__global__ __launch_bounds__(256) void scanA_kernel(const int* __restrict__ cnt,
                                                    int* __restrict__ rowptr,
                                                    float* __restrict__ dis,
                                                    int* __restrict__ bsum,
                                                    const int* __restrict__ batch,
                                                    int* __restrict__ gstart) {
    int t = threadIdx.x;
    int i = blockIdx.x * 256 + t;
    int d = 0;
    if (i < NN) {
        d = cnt[i * CSTR] + 1;                 // +1 self-loop (padded read)
        dis[i] = rsqrtf((float)d);
        // batch is sorted: thread i owns boundaries (batch[i-1], batch[i]]
        int b = batch[i];
        int bp = (i == 0) ? -1 : batch[i - 1];
        for (int g = bp + 1; g <= b; ++g) gstart[g] = i;
        if (i == NN - 1) {
            for (int g = b + 1; g <= GG; ++g) gstart[g] = NN;
        }
    }
    int total;
    int excl = block_excl_scan(d, t, &total);
    if (i < NN) rowptr[i] = excl;
    if (t == 0) bsum[blockIdx.x] = total;
}

// ---------------- scan BC ----------------
__global__ __launch_bounds__(256) void scanBC_kernel(int* __restrict__ rowptr,
                                                     const int* __restrict__ bsum) {
    __shared__ int sb[256];
    int t = threadIdx.x;
    int v = (t < SBLK) ? bsum[t] : 0;
    int total;
    int ex = block_excl_scan(v, t, &total);
    sb[t] = ex;
    __syncthreads();
    int myoff = sb[blockIdx.x];
    int i = blockIdx.x * 256 + t;
    if (i < NN) rowptr[i] += myoff;
    if (blockIdx.x == 0 && t == 0) rowptr[NN] = ETOT;
}

// ---------------- CSR fill: entry = src | fp16(dis[src])<<16 ----------------
__global__ void fill_kernel(const int* __restrict__ edge_src,
                            const int* __restrict__ edge_dst,
                            const float* __restrict__ dis,
                            const int* __restrict__ rowptr,
                            const int* __restrict__ seq,
                            uint_t* __restrict__ csr) {
    int idx = blockIdx.x * blockDim.x + threadIdx.x;
    if (idx < EE) {
        int s = edge_src[idx], d = edge_dst[idx];
        csr[rowptr[d] + seq[idx]] = (uint_t)s | ((uint_t)f2h(dis[s]) << 16);
    } else if (idx < ETOT) {
        int n = idx - EE;
        csr[rowptr[n + 1] - 1] = (uint_t)n | ((uint_t)f2h(dis[n]) << 16);
    }
}

// ---------------- agg1 + in-LDS layer-2, LDS-staged csr window ----------------
// Gather structure = proven R10 (1 node/wave, 8 edge slots x 8 feature-lanes,
// 2-deep). Inner loop accumulates f32x2 pairs -> v_pk_fma_f32 (16 VALU
// ops/entry instead of 24). Epilogue reads the same 16 floats via cast.
__global__ __launch_bounds__(256, 4) void agg1f_kernel(const unsigned char* __restrict__ hb8,
                                                       const int* __restrict__ rowptr,
                                                       const uint_t* __restrict__ csr,
                                                       const float* __restrict__ dis,
                                                       const float* __restrict__ b1,
                                                       const float* __restrict__ W2,
                                                       ushort_t* __restrict__ h2b) {
    __shared__ uint_t w2s[8 * 132];      // 4224 B
    __shared__ uint_t ecsr[A1CAP];       // 4096 B
    int t = threadIdx.x;
    int node0 = blockIdx.x * 4;
    int wave = t >> 6, lane = t & 63;
    int node = node0 + wave;
    int slot = lane >> 3, sub = lane & 7;
    int wbeg = rowptr[node0];
    int wcap = rowptr[node0 + 4];
    int e0 = rowptr[node], e1 = rowptr[node + 1];
    float dn = dis[node];
    {
        const float2* W2v = (const float2*)W2;   // W2v[k*8+sl] = W2[k][2sl..2sl+1]
        for (int i = t; i < HH * 8; i += 256) {
            int k = i >> 3, sl = i & 7;
            float2 wv = W2v[i];
            w2s[(k >> 4) * 132 + (k & 15) * 8 + sl] =
                (uint_t)f2bf(wv.x) | ((uint_t)f2bf(wv.y) << 16);
        }
    }
    int wlen = min(wcap - wbeg, A1CAP);
    for (int i = t; i < wlen; i += 256) ecsr[i] = csr[wbeg + i];
    __syncthreads();   // start-barrier: all waves arrive together (no skew)
    int wend = wbeg + wlen;

    f32x2 acc2[8];
    for (int j = 0; j < 8; j++) acc2[j] = (f32x2)(0.0f);
    for (int e = e0 + slot; e < e1; e += 16) {
        uint_t ent0;
        if (e < wend) ent0 = ecsr[e - wbeg]; else ent0 = csr[e];
        bool has2 = (e + 8) < e1;
        uint_t ent1 = ent0;
        if (has2) {
            if (e + 8 < wend) ent1 = ecsr[e + 8 - wbeg]; else ent1 = csr[e + 8];
        }
        uint4 hv0 = *(const uint4*)(hb8 + (size_t)(ent0 & 0xFFFFu) * HH + sub * 16);
        uint4 hv1 = has2 ? *(const uint4*)(hb8 + (size_t)(ent1 & 0xFFFFu) * HH + sub * 16)
                         : make_uint4(0, 0, 0, 0);
        float w0s = h2f((ushort_t)(ent0 >> 16));
        f32x2 w0 = { w0s, w0s };
        uint_t words0[4] = { hv0.x, hv0.y, hv0.z, hv0.w };
        for (int q = 0; q < 4; q++) {
            f32x2 lo = __builtin_amdgcn_cvt_pk_f32_fp8(words0[q], false);
            f32x2 hi = __builtin_amdgcn_cvt_pk_f32_fp8(words0[q], true);
            acc2[q * 2 + 0] += w0 * lo;     // v_pk_fma_f32
            acc2[q * 2 + 1] += w0 * hi;
        }
        if (has2) {
            float w1s = h2f((ushort_t)(ent1 >> 16));
            f32x2 w1 = { w1s, w1s };
            uint_t words1[4] = { hv1.x, hv1.y, hv1.z, hv1.w };
            for (int q = 0; q < 4; q++) {
                f32x2 lo = __builtin_amdgcn_cvt_pk_f32_fp8(words1[q], false);
                f32x2 hi = __builtin_amdgcn_cvt_pk_f32_fp8(words1[q], true);
                acc2[q * 2 + 0] += w1 * lo;
                acc2[q * 2 + 1] += w1 * hi;
            }
        }
    }
    float* accf = (float*)acc2;          // same 16-float layout as before
    for (int j = 0; j < 16; j++) {
        accf[j] += __shfl_xor(accf[j], 8);
        accf[j] += __shfl_xor(accf[j], 16);
        accf[j] += __shfl_xor(accf[j], 32);
    }
    const float4* b1v = (const float4*)(b1 + sub * 16);
    float4 bb[4] = { b1v[0], b1v[1], b1v[2], b1v[3] };
    const float* bbf = (const float*)bb;
    float p0 = 0.0f, p1 = 0.0f;
    int wbase = sub * 132 + slot;
    for (int j = 0; j < 16; j++) {
        float h = fmaxf(dn * accf[j] + bbf[j], 0.0f);
        uint_t w = w2s[wbase + j * 8];
        p0 += h * __uint_as_float(w << 16);            // W2[sub*16+j][2slot]
        p1 += h * __uint_as_float(w & 0xFFFF0000u);    // W2[sub*16+j][2slot+1]
    }
    p0 += __shfl_xor(p0, 1); p0 += __shfl_xor(p0, 2); p0 += __shfl_xor(p0, 4);
    p1 += __shfl_xor(p1, 1); p1 += __shfl_xor(p1, 2); p1 += __shfl_xor(p1, 4);
    if (sub == 0) {
        uint_t pk = (uint_t)f2bf(p0) | ((uint_t)f2bf(p1) << 16);
        *(uint_t*)(h2b + (size_t)node * CC + 2 * slot) = pk;
    }
}

// ---------------- agg2 + pool: LDS-staged csr window (R15 proven) -------------
__global__ __launch_bounds__(1024) void agg2pool_kernel(const ushort_t* __restrict__ h2b,
                                                        const int* __restrict__ rowptr,
                                                        const uint_t* __restrict__ csr,
                                                        const float* __restrict__ dis,
                                                        const float* __restrict__ b2,
                                                        const int* __restrict__ batch,
                                                        float* __restrict__ pooled) {
    __shared__ float vals[16][16];
    __shared__ int gid[16];
    __shared__ uint_t ecsr[A2CAP];       // 8192 B
    int wave = threadIdx.x >> 6, lane = threadIdx.x & 63;
    int node0 = blockIdx.x * 16;
    int node = node0 + wave;
    int slot = lane >> 3, sub = lane & 7;
    int wbeg = rowptr[node0];
    int wcap = rowptr[node0 + 16];
    int e0 = rowptr[node], e1 = rowptr[node + 1];
    float dn = dis[node];                // hoisted
    int   bg = batch[node];              // hoisted
    float b20 = b2[2 * sub], b21 = b2[2 * sub + 1];   // hoisted
    int wlen = min(wcap - wbeg, A2CAP);
    for (int i = threadIdx.x; i < wlen; i += 1024) ecsr[i] = csr[wbeg + i];
    __syncthreads();
    int wend = wbeg + wlen;

    float a0 = 0.0f, a1 = 0.0f;
    for (int e = e0 + slot; e < e1; e += 16) {
        uint_t ent0;
        if (e < wend) ent0 = ecsr[e - wbeg]; else ent0 = csr[e];
        bool has2 = (e + 8) < e1;
        uint_t ent1 = ent0;
        if (has2) {
            if (e + 8 < wend) ent1 = ecsr[e + 8 - wbeg]; else ent1 = csr[e + 8];
        }
        uint_t p0 = *(const uint_t*)(h2b + (size_t)(ent0 & 0xFFFFu) * CC + sub * 2);
        uint_t p1 = has2 ? *(const uint_t*)(h2b + (size_t)(ent1 & 0xFFFFu) * CC + sub * 2) : 0;
        float w0 = h2f((ushort_t)(ent0 >> 16));
        a0 += w0 * bf2f((ushort_t)(p0 & 0xFFFFu));
        a1 += w0 * bf2f((ushort_t)(p0 >> 16));
        if (has2) {
            float w1 = h2f((ushort_t)(ent1 >> 16));
            a0 += w1 * bf2f((ushort_t)(p1 & 0xFFFFu));
            a1 += w1 * bf2f((ushort_t)(p1 >> 16));
        }
    }
    a0 += __shfl_xor(a0, 8); a0 += __shfl_xor(a0, 16); a0 += __shfl_xor(a0, 32);
    a1 += __shfl_xor(a1, 8); a1 += __shfl_xor(a1, 16); a1 += __shfl_xor(a1, 32);
    if (slot == 0) {
        vals[wave][2 * sub]     = a0 * dn + b20;
        vals[wave][2 * sub + 1] = a1 * dn + b21;
        if (sub == 0) gid[wave] = bg;
    }
    __syncthreads();
    if (threadIdx.x < 16) {            // walker for channel threadIdx.x
        int c = threadIdx.x;
        float run = 0.0f;
        for (int i = 0; i < 16; i++) {
            run += vals[i][c];
            if (i == 15 || gid[i + 1] != gid[i]) {
                atomicAdd(&pooled[gid[i] * CC + c], run);
                run = 0.0f;
            }
        }
    }
}

// ---------------- mean + log_softmax (counts from gstart) ---------------------
__global__ void lsm_kernel(const float* __restrict__ pooled,
                           const int* __restrict__ gstart,
                           float* __restrict__ out) {
    int idx = blockIdx.x * blockDim.x + threadIdx.x;
    int g = idx >> 4, c = idx & 15;
    if (g >= GG) return;
    float cnt = (float)(gstart[g + 1] - gstart[g]);
    float v = pooled[g * CC + c] / fmaxf(cnt, 1.0f);
    float m = v;
    for (int off = 8; off >= 1; off >>= 1) m = fmaxf(m, __shfl_xor(m, off, 16));
    float s = expf(v - m);
    for (int off = 8; off >= 1; off >>= 1) s += __shfl_xor(s, off, 16);
    out[g * CC + c] = v - m - logf(s);
}

extern "C" void kernel_launch(void* const* d_in, const int* in_sizes, int n_in,
                              void* d_out, int out_size, void* d_ws, size_t ws_size,
                              hipStream_t stream) {
    const float* x  = (const float*)d_in[0];
    const float* W1 = (const float*)d_in[1];
    const float* b1 = (const float*)d_in[2];
    const float* W2 = (const float*)d_in[3];
    const float* b2 = (const float*)d_in[4];
    const int* edge_src = (const int*)d_in[5];
    const int* edge_dst = (const int*)d_in[6];
    const int* batch    = (const int*)d_in[7];
    float* out = (float*)d_out;

    char* ws = (char*)d_ws;
    size_t off = 0;
    auto alloc = [&](size_t bytes) {
        void* p = ws + off;
        off += (bytes + 255) & ~size_t(255);
        return p;
    };
    int*   cnt     = (int*)  alloc((size_t)NN * CSTR * 4);   // 3.2 MB padded
    float* dis     = (float*)alloc(NN * 4);
    int*   rowptr  = (int*)  alloc((NN + 1) * 4);
    int*   seq     = (int*)  alloc(EE * 4);
    int*   bsum    = (int*)  alloc(SBLK * 4);
    uint_t* csr    = (uint_t*)alloc((size_t)ETOT * 4);
    unsigned char* hb8 = (unsigned char*)alloc((size_t)NN * HH);
    ushort_t* h2b  = (ushort_t*)alloc((size_t)NN * CC * 2);
    float* pooled  = (float*)alloc(GG * CC * 4);
    int*   gstart  = (int*)  alloc((GG + 1) * 4);

    const int B = 256;
    init_kernel<<<(NN * CSTR + B - 1) / B, B, 0, stream>>>(cnt, pooled);
    cg1_kernel<<<CBLK + (NN + 63) / 64, B, 0, stream>>>(edge_dst, cnt, seq, x, W1, hb8);
    scanA_kernel<<<SBLK, B, 0, stream>>>(cnt, rowptr, dis, bsum, batch, gstart);
    scanBC_kernel<<<SBLK, B, 0, stream>>>(rowptr, bsum);
    fill_kernel<<<(ETOT + B - 1) / B, B, 0, stream>>>(edge_src, edge_dst, dis,
                                                      rowptr, seq, csr);
    agg1f_kernel<<<NN / 4, B, 0, stream>>>(hb8, rowptr, csr, dis, b1, W2, h2b);
    agg2pool_kernel<<<NN / 16, 1024, 0, stream>>>(h2b, rowptr, csr, dis, b2, batch, pooled);
    lsm_kernel<<<(GG * CC + B - 1) / B, B, 0, stream>>>(pooled, gstart, out);
}